// Round 3
// baseline (148.061 us; speedup 1.0000x reference)
//
#include <hip/hip_runtime.h>

// DTW loss: sum |preds[b, path_i[b,p]] - targets[b, path_j[b,p]]|_1 / (B*S)
// B=256, S=8192, P=16383. preds/targets fp32 (B,S,2); path_* int32 (B,P).
//
// R1 post-mortem: latency/request-rate bound on global gathers (~1 cacheline
// per CU-cycle on the TA path -> ~27 us floor), NOT HBM bytes. R2: stage each
// batch's 64 KB gather window in LDS as packed bf16x2 (exactly 64 KB for both
// arrays), prefetch all indices into registers so the two HBM streams overlap,
// then gather from LDS (ds_read_b32, ~9 cyc/wave even with random banks).
// Numerics: bf16 rounding errors have random sign; net loss error ~1e-5 << 9e-2.

#define BB 256
#define SS 8192
#define PP 16383
#define NT 1024          // threads per block
#define NIT 16           // ceil(PP / NT); 15 full iters + 1 guarded

__device__ __forceinline__ unsigned bfpack(float x, float y) {
    // round-to-nearest-even fp32 -> bf16, packed (y in high 16)
    unsigned ux = __float_as_uint(x), uy = __float_as_uint(y);
    ux = (ux + 0x7fffu + ((ux >> 16) & 1u)) >> 16;
    uy = (uy + 0x7fffu + ((uy >> 16) & 1u)) >> 16;
    return ux | (uy << 16);
}

__global__ __launch_bounds__(NT) void dtw_loss_kernel(
    const float* __restrict__ preds,
    const float* __restrict__ targets,
    const int* __restrict__ path_i,
    const int* __restrict__ path_j,
    float* __restrict__ out)
{
    __shared__ unsigned lds[2 * SS];   // [0,SS): preds bf16x2, [SS,2SS): targets

    const int b   = blockIdx.x;        // one block per batch
    const int tid = threadIdx.x;

    const float4* __restrict__ p4 = (const float4*)(preds   + (size_t)b * SS * 2);
    const float4* __restrict__ t4 = (const float4*)(targets + (size_t)b * SS * 2);
    const int*    __restrict__ pi = path_i + (size_t)b * PP;
    const int*    __restrict__ pj = path_j + (size_t)b * PP;

    // --- prefetch ALL indices into registers: these coalesced loads stream
    // from HBM concurrently with the staging loads below (issued first).
    int ii[NIT], jj[NIT];
    #pragma unroll
    for (int u = 0; u < NIT; ++u) {
        int k = u * NT + tid;
        k = (k < PP) ? k : (PP - 1);   // clamp; guarded at accumulate
        ii[u] = pi[k];
        jj[u] = pj[k];
    }

    // --- stage both 32 KB windows into LDS as packed bf16x2 ---
    #pragma unroll
    for (int u = 0; u < SS / (2 * NT); ++u) {   // 4 iters; float4 = 2 elements
        const int e = u * NT + tid;             // float4 index
        const float4 vp = p4[e];
        const float4 vt = t4[e];
        uint2 wp, wt;
        wp.x = bfpack(vp.x, vp.y);  wp.y = bfpack(vp.z, vp.w);
        wt.x = bfpack(vt.x, vt.y);  wt.y = bfpack(vt.z, vt.w);
        *(uint2*)&lds[2 * e]      = wp;         // ds_write_b64, stride-1
        *(uint2*)&lds[SS + 2 * e] = wt;
    }
    __syncthreads();

    // --- gather from LDS using the prefetched indices ---
    float acc = 0.0f;
    #pragma unroll
    for (int u = 0; u < NIT; ++u) {
        const unsigned up = lds[ii[u]];
        const unsigned ut = lds[SS + jj[u]];
        const float ax = __uint_as_float(up << 16);
        const float ay = __uint_as_float(up & 0xffff0000u);
        const float bx = __uint_as_float(ut << 16);
        const float by = __uint_as_float(ut & 0xffff0000u);
        const float d = fabsf(ax - bx) + fabsf(ay - by);
        if (u == NIT - 1) {
            if (tid < PP - (NIT - 1) * NT) acc += d;   // tail guard (1023 valid)
        } else {
            acc += d;
        }
    }

    // --- wave reduction, then one atomic per wave (LDS is fully used) ---
    #pragma unroll
    for (int off = 32; off > 0; off >>= 1)
        acc += __shfl_down(acc, off, 64);
    if ((tid & 63) == 0)
        atomicAdd(out, acc * (1.0f / ((float)BB * (float)SS)));  // 2^-21 exact
}

extern "C" void kernel_launch(void* const* d_in, const int* in_sizes, int n_in,
                              void* d_out, int out_size, void* d_ws, size_t ws_size,
                              hipStream_t stream) {
    const float* preds   = (const float*)d_in[0];
    const float* targets = (const float*)d_in[1];
    const int*   path_i  = (const int*)d_in[2];
    const int*   path_j  = (const int*)d_in[3];
    float* out = (float*)d_out;

    // d_out is poisoned 0xAA before every launch; stream-ordered memset is
    // graph-capture legal.
    hipMemsetAsync(out, 0, sizeof(float), stream);

    dtw_loss_kernel<<<BB, NT, 0, stream>>>(preds, targets, path_i, path_j, out);
}

// Round 4
// 104.065 us; speedup vs baseline: 1.4228x; 1.4228x over previous
//
#include <hip/hip_runtime.h>

// DTW loss: sum |preds[b, path_i[b,p]] - targets[b, path_j[b,p]]|_1 / (B*S)
// B=256, S=8192, P=16383. preds/targets fp32 (B,S,2); path_* int32 (B,P).
//
// R2 post-mortem: (1) same-address fp32 atomicAdd tail (4096 wave-atomics ~
// 30 cyc each serialized at the home L2 slice ~= 51 us) dominated R0-R2;
// (2) index prefetch sank past __syncthreads (VGPR=36), serializing chains.
// R3: one atomic per block into 8 XCD-keyed d_ws slots + tiny final kernel;
// asm-pin the packed index prefetch; 512 blocks (2/CU) so one block's LDS
// gather overlaps the other's HBM staging.

#define BB 256
#define SS 8192
#define PP 16383
#define NT 1024
#define HALF 8192        // pairs per block (chunk 0); chunk 1 gets 8191
#define NIT 8            // HALF / NT

__device__ __forceinline__ unsigned bfpack(float x, float y) {
    // round-to-nearest-even fp32 -> bf16, packed (y in high 16)
    unsigned ux = __float_as_uint(x), uy = __float_as_uint(y);
    ux = (ux + 0x7fffu + ((ux >> 16) & 1u)) >> 16;
    uy = (uy + 0x7fffu + ((uy >> 16) & 1u)) >> 16;
    return ux | (uy << 16);
}

__global__ __launch_bounds__(NT, 8) void dtw_loss_kernel(
    const float* __restrict__ preds,
    const float* __restrict__ targets,
    const int* __restrict__ path_i,
    const int* __restrict__ path_j,
    float* __restrict__ ws)   // 8 partial-sum slots, pre-zeroed
{
    __shared__ unsigned lds[2 * SS];   // 64 KB: [0,SS) preds, [SS,2SS) targets

    const int tid   = threadIdx.x;
    const int xcd   = blockIdx.x & 7;          // round-robin XCD assignment
    const int slot  = blockIdx.x >> 3;         // 0..63
    const int batch = xcd + 8 * (slot >> 1);   // 0..255, batch%8 == xcd
    const int chunk = slot & 1;                // 0..1

    const float4* __restrict__ p4 = (const float4*)(preds   + (size_t)batch * SS * 2);
    const float4* __restrict__ t4 = (const float4*)(targets + (size_t)batch * SS * 2);
    const int*    __restrict__ pi = path_i + (size_t)batch * PP + chunk * HALF;
    const int*    __restrict__ pj = path_j + (size_t)batch * PP + chunk * HALF;
    const int npairs = chunk ? (PP - HALF) : HALF;   // 8191 : 8192

    // --- prefetch this block's indices, packed 16+16 (S=8192 < 2^16) ---
    unsigned pk[NIT];
    #pragma unroll
    for (int u = 0; u < NIT; ++u) {
        int k = u * NT + tid;
        if (u == NIT - 1) k = min(k, npairs - 1);   // only last iter can overrun
        pk[u] = ((unsigned)pi[k] & 0xffffu) | ((unsigned)pj[k] << 16);
    }

    // --- stage both 32 KB windows into LDS as packed bf16x2 ---
    #pragma unroll
    for (int u = 0; u < 4; ++u) {
        const int e = u * NT + tid;              // float4 index, [0,4096)
        const float4 vp = p4[e];
        const float4 vt = t4[e];
        uint2 wp, wt;
        wp.x = bfpack(vp.x, vp.y);  wp.y = bfpack(vp.z, vp.w);
        wt.x = bfpack(vt.x, vt.y);  wt.y = bfpack(vt.z, vt.w);
        *(uint2*)&lds[2 * e]      = wp;
        *(uint2*)&lds[SS + 2 * e] = wt;
    }

    // Pin prefetched indices in VGPRs so the loads cannot sink past the
    // barrier (R2's failure mode: compiler rematerialized them in phase 2).
    #pragma unroll
    for (int u = 0; u < NIT; ++u)
        asm volatile("" : "+v"(pk[u]));
    __syncthreads();

    // --- gather from LDS: 16 independent ds_read_b32 per thread ---
    float acc = 0.0f;
    #pragma unroll
    for (int u = 0; u < NIT; ++u) {
        const unsigned i = pk[u] & 0xffffu;
        const unsigned j = pk[u] >> 16;
        const unsigned up = lds[i];
        const unsigned ut = lds[SS + j];
        const float ax = __uint_as_float(up << 16);
        const float ay = __uint_as_float(up & 0xffff0000u);
        const float bx = __uint_as_float(ut << 16);
        const float by = __uint_as_float(ut & 0xffff0000u);
        const float d = fabsf(ax - bx) + fabsf(ay - by);
        if (u < NIT - 1 || u * NT + tid < npairs) acc += d;
    }

    // --- wave reduce, then block reduce via (reused) LDS: ONE atomic/block ---
    #pragma unroll
    for (int off = 32; off > 0; off >>= 1)
        acc += __shfl_down(acc, off, 64);

    __syncthreads();                       // all gather reads done; safe to clobber
    if ((tid & 63) == 0) lds[tid >> 6] = __float_as_uint(acc);
    __syncthreads();
    if (tid < 16) {
        float s = __uint_as_float(lds[tid]);
        s += __shfl_down(s, 8, 64);
        s += __shfl_down(s, 4, 64);
        s += __shfl_down(s, 2, 64);
        s += __shfl_down(s, 1, 64);
        if (tid == 0) atomicAdd(&ws[xcd], s);   // 64 same-address atomics/slot
    }
}

__global__ void dtw_final_kernel(const float* __restrict__ ws, float* __restrict__ out) {
    if (threadIdx.x == 0) {
        float s = 0.0f;
        #pragma unroll
        for (int i = 0; i < 8; ++i) s += ws[i];
        out[0] = s * (1.0f / ((float)BB * (float)SS));   // *2^-21, exact scale
    }
}

extern "C" void kernel_launch(void* const* d_in, const int* in_sizes, int n_in,
                              void* d_out, int out_size, void* d_ws, size_t ws_size,
                              hipStream_t stream) {
    const float* preds   = (const float*)d_in[0];
    const float* targets = (const float*)d_in[1];
    const int*   path_i  = (const int*)d_in[2];
    const int*   path_j  = (const int*)d_in[3];
    float* ws  = (float*)d_ws;
    float* out = (float*)d_out;

    hipMemsetAsync(ws, 0, 8 * sizeof(float), stream);   // ws re-poisoned 0xAA

    dtw_loss_kernel<<<BB * 2, NT, 0, stream>>>(preds, targets, path_i, path_j, ws);
    dtw_final_kernel<<<1, 64, 0, stream>>>(ws, out);
}

// Round 5
// 103.688 us; speedup vs baseline: 1.4279x; 1.0036x over previous
//
#include <hip/hip_runtime.h>

// DTW loss: sum |preds[b, path_i[b,p]] - targets[b, path_j[b,p]]|_1 / (B*S)
// B=256, S=8192, P=16383. preds/targets fp32 (B,S,2); path_* int32 (B,P).
//
// R3 post-mortem: kernel ~35 us vs 10.6 us stream floor. Costs: windows
// fetched twice (2 blocks/batch), bf16-pack VALU round-trip on staging, and
// phase-locked co-resident blocks. R4: one block per batch (67 MB total
// stream), fp32 staging via global_load_lds width-16 DMA (no VGPR round-trip,
// exact numerics), random ds_read_b64 gathers from 128 KB LDS.

#define BB 256
#define SS 8192
#define PP 16383
#define NT 1024
#define NIT 16           // ceil(PP / NT): 15 full iters + 1 guarded

typedef float f32x4 __attribute__((ext_vector_type(4)));

__global__ __launch_bounds__(NT, 4) void dtw_loss_kernel(
    const float* __restrict__ preds,
    const float* __restrict__ targets,
    const int* __restrict__ path_i,
    const int* __restrict__ path_j,
    float* __restrict__ ws)   // 8 partial-sum slots, pre-zeroed
{
    // 128 KB: preds window fp32 float2 in [0, 2*SS) floats, targets after.
    __shared__ float lds[4 * SS];
    __shared__ float wred[16];

    const int tid   = threadIdx.x;
    const int batch = blockIdx.x;          // one block per batch
    const int wave  = tid >> 6;            // 0..15
    const int lane  = tid & 63;

    const char* pbase = (const char*)(preds   + (size_t)batch * SS * 2);  // 64 KB
    const char* tbase = (const char*)(targets + (size_t)batch * SS * 2);  // 64 KB
    const int* __restrict__ pi = path_i + (size_t)batch * PP;
    const int* __restrict__ pj = path_j + (size_t)batch * PP;

    // --- stage both 64 KB fp32 windows via direct global->LDS DMA ---
    // Each wave: 4 x 1 KB instrs per array. HW deposits at lds_base + lane*16.
    #pragma unroll
    for (int u = 0; u < 4; ++u) {
        const int off = (wave * 4 + u) * 1024;          // byte offset in window
        __builtin_amdgcn_global_load_lds(
            (const __attribute__((address_space(1))) void*)(pbase + off + lane * 16),
            (__attribute__((address_space(3))) void*)((char*)lds + off),
            16, 0, 0);
        __builtin_amdgcn_global_load_lds(
            (const __attribute__((address_space(1))) void*)(tbase + off + lane * 16),
            (__attribute__((address_space(3))) void*)((char*)lds + 65536 + off),
            16, 0, 0);
    }

    // --- prefetch ALL indices (packed 16+16; S=8192 < 2^16), pinned in VGPRs
    // so the loads cannot sink past the barrier (R2 failure mode).
    unsigned pk[NIT];
    #pragma unroll
    for (int u = 0; u < NIT; ++u) {
        int k = u * NT + tid;
        if (u == NIT - 1) k = min(k, PP - 1);
        pk[u] = ((unsigned)pi[k]) | ((unsigned)pj[k] << 16);
    }
    #pragma unroll
    for (int u = 0; u < NIT; ++u)
        asm volatile("" : "+v"(pk[u]));

    __syncthreads();   // drains vmcnt(0): all DMA deposits + index loads done

    // --- gather from LDS: 32 independent ds_read_b64 per thread ---
    const float2* __restrict__ lp = (const float2*)lds;            // preds
    const float2* __restrict__ lt = (const float2*)(lds + 2 * SS); // targets
    float acc = 0.0f;
    #pragma unroll
    for (int u = 0; u < NIT; ++u) {
        const unsigned i = pk[u] & 0xffffu;
        const unsigned j = pk[u] >> 16;
        const float2 a = lp[i];
        const float2 b = lt[j];
        const float d = fabsf(a.x - b.x) + fabsf(a.y - b.y);
        if (u < NIT - 1 || u * NT + tid < PP) acc += d;   // tail: 1023 valid
    }

    // --- wave reduce -> block reduce -> ONE atomic per block (8 XCD slots) ---
    #pragma unroll
    for (int off = 32; off > 0; off >>= 1)
        acc += __shfl_down(acc, off, 64);
    if (lane == 0) wred[wave] = acc;
    __syncthreads();
    if (tid < 16) {
        float s = wred[tid];
        s += __shfl_down(s, 8, 64);
        s += __shfl_down(s, 4, 64);
        s += __shfl_down(s, 2, 64);
        s += __shfl_down(s, 1, 64);
        if (tid == 0) atomicAdd(&ws[blockIdx.x & 7], s);  // 32 atomics/slot
    }
}

__global__ void dtw_final_kernel(const float* __restrict__ ws, float* __restrict__ out) {
    if (threadIdx.x == 0) {
        float s = 0.0f;
        #pragma unroll
        for (int i = 0; i < 8; ++i) s += ws[i];
        out[0] = s * (1.0f / ((float)BB * (float)SS));   // *2^-21, exact scale
    }
}

extern "C" void kernel_launch(void* const* d_in, const int* in_sizes, int n_in,
                              void* d_out, int out_size, void* d_ws, size_t ws_size,
                              hipStream_t stream) {
    const float* preds   = (const float*)d_in[0];
    const float* targets = (const float*)d_in[1];
    const int*   path_i  = (const int*)d_in[2];
    const int*   path_j  = (const int*)d_in[3];
    float* ws  = (float*)d_ws;
    float* out = (float*)d_out;

    hipMemsetAsync(ws, 0, 8 * sizeof(float), stream);   // ws re-poisoned 0xAA

    dtw_loss_kernel<<<BB, NT, 0, stream>>>(preds, targets, path_i, path_j, ws);
    dtw_final_kernel<<<1, 64, 0, stream>>>(ws, out);
}

// Round 6
// 102.835 us; speedup vs baseline: 1.4398x; 1.0083x over previous
//
#include <hip/hip_runtime.h>

// DTW loss: sum |preds[b, path_i[b,p]] - targets[b, path_j[b,p]]|_1 / (B*S)
// B=256, S=8192, P=16383. preds/targets fp32 (B,S,2); path_* int32 (B,P).
//
// R4 post-mortem: R3 (98 MB, bf16 pack, 2 blk/CU) and R4 (67 MB, DMA staging,
// 1 blk/CU) both land at K~30-35 us vs a ~17 us model -> bytes/staging no
// longer binding; residual unattributed (kernel invisible in rocprof top-5
// behind the harness's 268 MB poison fills). R5 strips the last known serial
// costs: no memset node (unique ws slot per block, plain store, no atomics),
// one-wave final reduce. If dur_us doesn't move, next round self-measures K
// by running the main kernel twice.

#define BB 256
#define SS 8192
#define PP 16383
#define NT 1024
#define NIT 16           // ceil(PP / NT): 15 full iters + 1 guarded

__global__ __launch_bounds__(NT, 4) void dtw_loss_kernel(
    const float* __restrict__ preds,
    const float* __restrict__ targets,
    const int* __restrict__ path_i,
    const int* __restrict__ path_j,
    float* __restrict__ partial)   // 256 slots, one per block; no init needed
{
    // 128 KB: preds window fp32 float2 in [0, 2*SS) floats, targets after.
    __shared__ float lds[4 * SS];
    __shared__ float wred[16];

    const int tid   = threadIdx.x;
    const int batch = blockIdx.x;          // one block per batch
    const int wave  = tid >> 6;            // 0..15
    const int lane  = tid & 63;

    const char* pbase = (const char*)(preds   + (size_t)batch * SS * 2);  // 64 KB
    const char* tbase = (const char*)(targets + (size_t)batch * SS * 2);  // 64 KB
    const int* __restrict__ pi = path_i + (size_t)batch * PP;
    const int* __restrict__ pj = path_j + (size_t)batch * PP;

    // --- stage both 64 KB fp32 windows via direct global->LDS DMA ---
    // Each wave: 4 x 1 KB instrs per array; HW deposits at lds_base + lane*16.
    #pragma unroll
    for (int u = 0; u < 4; ++u) {
        const int off = (wave * 4 + u) * 1024;          // byte offset in window
        __builtin_amdgcn_global_load_lds(
            (const __attribute__((address_space(1))) void*)(pbase + off + lane * 16),
            (__attribute__((address_space(3))) void*)((char*)lds + off),
            16, 0, 0);
        __builtin_amdgcn_global_load_lds(
            (const __attribute__((address_space(1))) void*)(tbase + off + lane * 16),
            (__attribute__((address_space(3))) void*)((char*)lds + 65536 + off),
            16, 0, 0);
    }

    // --- prefetch ALL indices (packed 16+16; S=8192 < 2^16), pinned in VGPRs
    // so the loads cannot sink past the barrier (R2 failure mode).
    unsigned pk[NIT];
    #pragma unroll
    for (int u = 0; u < NIT; ++u) {
        int k = u * NT + tid;
        if (u == NIT - 1) k = min(k, PP - 1);
        pk[u] = ((unsigned)pi[k]) | ((unsigned)pj[k] << 16);
    }
    #pragma unroll
    for (int u = 0; u < NIT; ++u)
        asm volatile("" : "+v"(pk[u]));

    __syncthreads();   // drains vmcnt(0): all DMA deposits + index loads done

    // --- gather from LDS: 32 independent ds_read_b64 per thread ---
    const float2* __restrict__ lp = (const float2*)lds;            // preds
    const float2* __restrict__ lt = (const float2*)(lds + 2 * SS); // targets
    float acc = 0.0f;
    #pragma unroll
    for (int u = 0; u < NIT; ++u) {
        const unsigned i = pk[u] & 0xffffu;
        const unsigned j = pk[u] >> 16;
        const float2 a = lp[i];
        const float2 b = lt[j];
        const float d = fabsf(a.x - b.x) + fabsf(a.y - b.y);
        if (u < NIT - 1 || u * NT + tid < PP) acc += d;   // tail: 1023 valid
    }

    // --- wave reduce -> block reduce -> ONE plain store per block ---
    #pragma unroll
    for (int off = 32; off > 0; off >>= 1)
        acc += __shfl_down(acc, off, 64);
    if (lane == 0) wred[wave] = acc;
    __syncthreads();
    if (tid < 16) {
        float s = wred[tid];
        s += __shfl_down(s, 8, 64);
        s += __shfl_down(s, 4, 64);
        s += __shfl_down(s, 2, 64);
        s += __shfl_down(s, 1, 64);
        if (tid == 0) partial[batch] = s;   // unique slot: no atomic, no init
    }
}

__global__ __launch_bounds__(64) void dtw_final_kernel(
    const float* __restrict__ partial, float* __restrict__ out)
{
    // 256 partials = 64 lanes x float4; kernel boundary guarantees visibility.
    const float4 v = ((const float4*)partial)[threadIdx.x];
    float s = (v.x + v.y) + (v.z + v.w);
    #pragma unroll
    for (int off = 32; off > 0; off >>= 1)
        s += __shfl_down(s, off, 64);
    if (threadIdx.x == 0)
        out[0] = s * (1.0f / ((float)BB * (float)SS));   // *2^-21, exact scale
}

extern "C" void kernel_launch(void* const* d_in, const int* in_sizes, int n_in,
                              void* d_out, int out_size, void* d_ws, size_t ws_size,
                              hipStream_t stream) {
    const float* preds   = (const float*)d_in[0];
    const float* targets = (const float*)d_in[1];
    const int*   path_i  = (const int*)d_in[2];
    const int*   path_j  = (const int*)d_in[3];
    float* partial = (float*)d_ws;    // 256 floats; every slot written each call
    float* out     = (float*)d_out;

    dtw_loss_kernel<<<BB, NT, 0, stream>>>(preds, targets, path_i, path_j, partial);
    dtw_final_kernel<<<1, 64, 0, stream>>>(partial, out);
}